// Round 14
// baseline (342.107 us; speedup 1.0000x reference)
//
#include <hip/hip_runtime.h>
#include <hip/hip_cooperative_groups.h>
#include <float.h>
#include <math.h>

namespace cg = cooperative_groups;

#define NUM_USERS 100000
#define NUM_ITEMS 50000
#define NNODES    150000
#define DIM       64
#define NEDGE     2000000
#define BATCH     1024
#define SEL_CAP   (1 << 18)

#define SLICES   1024                   // edge slices (all blocks resident: 4/CU)
#define EPS      1956                   // ceil(NEDGE/SLICES) rounded to x4
#define NBUK     293                    // buckets of 512 nodes (293*512=150016)
#define BCAP     8192                   // per-bucket CSR arena (exp 6826, +16 sigma)
#define SCAP     16                     // fixed slots per (bucket, slice); exp 6.7
#define OVF_CAP  4096                   // global overflow list (exp ~200 edges/run)

__device__ __forceinline__ float wave_sum64(float v) {
    #pragma unroll
    for (int off = 32; off > 0; off >>= 1) v += __shfl_xor(v, off, 64);
    return v;
}

__device__ __forceinline__ float bf2f(unsigned short s) {
    return __uint_as_float(((unsigned int)s) << 16);
}
__device__ __forceinline__ unsigned short f2bf(float f) {   // RNE
    unsigned int u = __float_as_uint(f);
    return (unsigned short)((u + 0x7fffu + ((u >> 16) & 1u)) >> 16);
}

// ---- bucket sort, single pass, deterministic (bucket,slice) slotting -----

__global__ __launch_bounds__(512) void sort_kernel(
        const int* __restrict__ row, const int* __restrict__ col,
        const int* __restrict__ ucnt,
        unsigned char* __restrict__ cntC8, unsigned char* __restrict__ cntR8,
        unsigned int* __restrict__ midC2, unsigned short* __restrict__ midR2,
        uint2* __restrict__ ovfC, unsigned int* __restrict__ ovfR,
        int* __restrict__ novfC_g, int* __restrict__ novfR_g,
        int* __restrict__ n_sel, int* __restrict__ sel_col, float* __restrict__ sel_w) {
    __shared__ unsigned int hc[NBUK], hr[NBUK];
    __shared__ unsigned int   stC[NBUK * SCAP];
    __shared__ unsigned short stR[NBUK * SCAP];
    __shared__ int lcnt, lbase;
    __shared__ int2 buf[256];
    int blk = blockIdx.x, t = threadIdx.x;
    for (int i = t; i < NBUK; i += 512) { hc[i] = 0; hr[i] = 0; }
    if (t == 0) lcnt = 0;
    __syncthreads();
    int e0 = blk * EPS;
    int e1 = e0 + EPS; if (e1 > NEDGE) e1 = NEDGE;
    for (int base = e0 + t * 4; base < e1; base += 2048) {
        if (base + 4 <= e1) {
            int4 r4 = *(const int4*)(row + base);
            int4 c4 = *(const int4*)(col + base);
            #pragma unroll
            for (int q = 0; q < 4; ++q) {
                int c = (q == 0) ? c4.x : (q == 1) ? c4.y : (q == 2) ? c4.z : c4.w;
                int r = (q == 0) ? r4.x : (q == 1) ? r4.y : (q == 2) ? r4.z : r4.w;
                int bc = c >> 9;
                unsigned int kc = atomicAdd(&hc[bc], 1u);
                unsigned int v = ((unsigned int)(c & 511) << 18) | (unsigned int)r;
                if (kc < SCAP) stC[bc * SCAP + kc] = v;
                else { int i = atomicAdd(novfC_g, 1); if (i < OVF_CAP) ovfC[i] = make_uint2((unsigned int)bc, v); }
                int br = r >> 9;
                unsigned int kr = atomicAdd(&hr[br], 1u);
                if (kr < SCAP) stR[br * SCAP + kr] = (unsigned short)(r & 511);
                else { int i = atomicAdd(novfR_g, 1); if (i < OVF_CAP) ovfR[i] = ((unsigned int)br << 9) | (unsigned int)(r & 511); }
                int u = ucnt[r];
                if (u > 0) { int i = atomicAdd(&lcnt, 1); if (i < 256) buf[i] = make_int2(c, u); }
            }
        } else {
            for (int e = base; e < e1; ++e) {
                int r = row[e], c = col[e];
                int bc = c >> 9;
                unsigned int kc = atomicAdd(&hc[bc], 1u);
                unsigned int v = ((unsigned int)(c & 511) << 18) | (unsigned int)r;
                if (kc < SCAP) stC[bc * SCAP + kc] = v;
                else { int i = atomicAdd(novfC_g, 1); if (i < OVF_CAP) ovfC[i] = make_uint2((unsigned int)bc, v); }
                int br = r >> 9;
                unsigned int kr = atomicAdd(&hr[br], 1u);
                if (kr < SCAP) stR[br * SCAP + kr] = (unsigned short)(r & 511);
                else { int i = atomicAdd(novfR_g, 1); if (i < OVF_CAP) ovfR[i] = ((unsigned int)br << 9) | (unsigned int)(r & 511); }
                int u = ucnt[r];
                if (u > 0) { int i = atomicAdd(&lcnt, 1); if (i < 256) buf[i] = make_int2(c, u); }
            }
        }
    }
    __syncthreads();
    for (int j = t; j < NBUK * SCAP; j += 512) {
        int b = j >> 4, k = j & (SCAP - 1);
        unsigned int cc = hc[b]; if (cc > SCAP) cc = SCAP;
        if ((unsigned int)k < cc)
            midC2[(size_t)b * (SLICES * SCAP) + blk * SCAP + k] = stC[j];
        unsigned int cr = hr[b]; if (cr > SCAP) cr = SCAP;
        if ((unsigned int)k < cr)
            midR2[(size_t)b * (SLICES * SCAP) + blk * SCAP + k] = stR[j];
    }
    if (t < NBUK) {
        unsigned int cc = hc[t]; if (cc > SCAP) cc = SCAP;
        unsigned int cr = hr[t]; if (cr > SCAP) cr = SCAP;
        cntC8[(size_t)blk * NBUK + t] = (unsigned char)cc;
        cntR8[(size_t)blk * NBUK + t] = (unsigned char)cr;
    }
    if (t == 0) {
        int c = lcnt; c = c < 256 ? c : 256;
        lbase = atomicAdd(n_sel, c);
    }
    __syncthreads();
    int c = lcnt; c = c < 256 ? c : 256;
    int b = lbase;
    for (int i = t; i < c; i += 512) {
        int o = b + i;
        if (o < SEL_CAP) { sel_col[o] = buf[i].x; sel_w[o] = (float)buf[i].y; }
    }
}

// ---- stage 2, split grid: blocks [0,NBUK) col CSR; [NBUK,2*NBUK) row+cvt --
// Col: the count-pass atomic returns each entry's RANK; entries+ranks are
// held in registers (statically indexed), so after the scan the scatter is
// a direct register write — no stage buffer, no second atomic pass.

__global__ __launch_bounds__(1024) void bfinal_kernel(
        const unsigned int* __restrict__ midC2, const unsigned char* __restrict__ cntC8,
        const unsigned short* __restrict__ midR2, const unsigned char* __restrict__ cntR8,
        const uint2* __restrict__ ovfC, const unsigned int* __restrict__ ovfR,
        const int* __restrict__ novfC_g, const int* __restrict__ novfR_g,
        const float4* __restrict__ embed,
        int* __restrict__ rptr, int* __restrict__ rend, int* __restrict__ src_sorted,
        float* __restrict__ dinv, float* __restrict__ dinv2,
        uint2* __restrict__ y0) {
    __shared__ int cnt[512], sm[512];
    __shared__ unsigned char lc[SLICES];
    __shared__ float dinvL[512];
    __shared__ int ovN;
    __shared__ uint2 ovL[64];        // (value, rank) of overflow entries here
    int bb = blockIdx.x, t = threadIdx.x;
    if (bb < NBUK) {
        // ---------------- col CSR for bucket b ----------------
        int b = bb;
        if (t < SLICES) lc[t] = cntC8[(size_t)t * NBUK + b];
        if (t < 512) cnt[t] = 0;
        if (t == 0) ovN = 0;
        __syncthreads();
        size_t cbase = (size_t)b * (SLICES * SCAP);
        unsigned int vbuf[16];
        int kbuf[16];
        #pragma unroll
        for (int it = 0; it < 16; ++it) {
            int j = t + it * 1024;
            unsigned int v = 0xFFFFFFFFu;
            int k = 0;
            if ((unsigned int)(j & (SCAP - 1)) < (unsigned int)lc[j >> 4]) {
                v = midC2[cbase + j];
                k = atomicAdd(&cnt[v >> 18], 1);
            }
            vbuf[it] = v; kbuf[it] = k;
        }
        int noC = *novfC_g; if (noC > OVF_CAP) noC = OVF_CAP;
        for (int i = t; i < noC; i += 1024) {
            if ((int)ovfC[i].x == b) {
                unsigned int v = ovfC[i].y;
                int k = atomicAdd(&cnt[v >> 18], 1);
                int id = atomicAdd(&ovN, 1);
                if (id < 64) ovL[id] = make_uint2(v, (unsigned int)k);
            }
        }
        __syncthreads();
        if (t < 512) sm[t] = cnt[t];
        __syncthreads();
        for (int off = 1; off < 512; off <<= 1) {
            int v = 0;
            if (t < 512 && t >= off) v = sm[t - off];
            __syncthreads();
            if (t < 512) sm[t] += v;
            __syncthreads();
        }
        int s0 = b * BCAP;
        if (t < 512) {
            int excl = s0 + sm[t] - cnt[t];
            int n = b * 512 + t;
            if (n < NNODES) { rptr[n] = excl; rend[n] = s0 + sm[t]; }
        }
        __syncthreads();
        // direct scatter from registers: dst = excl[node] + rank
        #pragma unroll
        for (int it = 0; it < 16; ++it) {
            unsigned int v = vbuf[it];
            if (v != 0xFFFFFFFFu) {
                int node = (int)(v >> 18);
                int dst = s0 + sm[node] - cnt[node] + kbuf[it];
                src_sorted[dst] = (int)(v & 0x3FFFFu);
            }
        }
        int on = ovN; on = on < 64 ? on : 64;
        for (int i = t; i < on; i += 1024) {
            unsigned int v = ovL[i].x;
            int node = (int)(v >> 18);
            int dst = s0 + sm[node] - cnt[node] + (int)ovL[i].y;
            src_sorted[dst] = (int)(v & 0x3FFFFu);
        }
    } else {
        // ---------------- row deg + dinv + cvt for bucket b ----------------
        int b = bb - NBUK;
        if (t < SLICES) lc[t] = cntR8[(size_t)t * NBUK + b];
        if (t < 512) cnt[t] = 0;
        __syncthreads();
        size_t cbase = (size_t)b * (SLICES * SCAP);
        for (int j = t; j < SLICES * SCAP; j += 1024) {
            if ((unsigned int)(j & (SCAP - 1)) < (unsigned int)lc[j >> 4])
                atomicAdd(&cnt[midR2[cbase + j]], 1);
        }
        int noR = *novfR_g; if (noR > OVF_CAP) noR = OVF_CAP;
        for (int i = t; i < noR; i += 1024) {
            unsigned int pv = ovfR[i];
            if ((int)(pv >> 9) == b) atomicAdd(&cnt[pv & 511u], 1);
        }
        if (b == 0 && t < 16) y0[(size_t)NNODES * 16 + t] = make_uint2(0u, 0u); // sentinel
        __syncthreads();
        if (t < 512) {
            int n = b * 512 + t;
            if (n < NNODES) {
                float d = fmaxf((float)cnt[t], 1.0f);
                float di = rsqrtf(d);
                dinv[n] = di; dinv2[n] = 1.0f / d;
                dinvL[t] = di;
            }
        }
        __syncthreads();
        int nbase = b * 512;
        int nmax = NNODES - nbase; if (nmax > 512) nmax = 512;
        if (nmax < 0) nmax = 0;
        for (int i = t; i < nmax * 16; i += 1024) {
            int ln = i >> 4, slot = i & 15;
            float d = dinvL[ln];
            float4 v = embed[(size_t)(nbase + ln) * 16 + slot];
            unsigned int w0 = (unsigned int)f2bf(v.x * d) | ((unsigned int)f2bf(v.y * d) << 16);
            unsigned int w1 = (unsigned int)f2bf(v.z * d) | ((unsigned int)f2bf(v.w * d) << 16);
            y0[(size_t)(nbase + ln) * 16 + slot] = make_uint2(w0, w1);
        }
    }
}

// ---- propagation: 8 lanes/node, uint4 (8 bf16)/lane; src-prefetch pipeline,
//      parallel sentinel tail (node NNODES is an always-zero row) -----------

#define ACC8(V) do { \
    a0 += __uint_as_float((V).x << 16); a1 += __uint_as_float((V).x & 0xffff0000u); \
    a2 += __uint_as_float((V).y << 16); a3 += __uint_as_float((V).y & 0xffff0000u); \
    a4 += __uint_as_float((V).z << 16); a5 += __uint_as_float((V).z & 0xffff0000u); \
    a6 += __uint_as_float((V).w << 16); a7 += __uint_as_float((V).w & 0xffff0000u); \
} while (0)

__device__ __forceinline__ void prop_node(
        const uint4* __restrict__ x_in, uint4* __restrict__ x_out,
        const int* __restrict__ ptr, const int* __restrict__ rend,
        const int* __restrict__ src,
        const float* __restrict__ scale, int node, int sl) {
    int i = ptr[node], e = rend[node];
    float sc = scale[node];
    float a0 = 0.f, a1 = 0.f, a2 = 0.f, a3 = 0.f;
    float a4 = 0.f, a5 = 0.f, a6 = 0.f, a7 = 0.f;
    int p0, p1, p2, p3;
    if (i + 4 <= e) { p0 = src[i]; p1 = src[i + 1]; p2 = src[i + 2]; p3 = src[i + 3]; }
    while (i + 8 <= e) {
        uint4 w0 = x_in[p0 * 8 + sl];
        uint4 w1 = x_in[p1 * 8 + sl];
        uint4 w2 = x_in[p2 * 8 + sl];
        uint4 w3 = x_in[p3 * 8 + sl];
        p0 = src[i + 4]; p1 = src[i + 5]; p2 = src[i + 6]; p3 = src[i + 7];
        i += 4;
        ACC8(w0); ACC8(w1); ACC8(w2); ACC8(w3);
    }
    if (i + 4 <= e) {
        uint4 w0 = x_in[p0 * 8 + sl];
        uint4 w1 = x_in[p1 * 8 + sl];
        uint4 w2 = x_in[p2 * 8 + sl];
        uint4 w3 = x_in[p3 * 8 + sl];
        i += 4;
        ACC8(w0); ACC8(w1); ACC8(w2); ACC8(w3);
    }
    if (i < e) {               // tail 1..3: clamp to sentinel zero row
        int q0 = src[i];
        int q1 = (i + 1 < e) ? src[i + 1] : NNODES;
        int q2 = (i + 2 < e) ? src[i + 2] : NNODES;
        uint4 w0 = x_in[q0 * 8 + sl];
        uint4 w1 = x_in[q1 * 8 + sl];
        uint4 w2 = x_in[q2 * 8 + sl];
        ACC8(w0); ACC8(w1); ACC8(w2);
    }
    uint4 o;
    o.x = (unsigned int)f2bf(a0 * sc) | ((unsigned int)f2bf(a1 * sc) << 16);
    o.y = (unsigned int)f2bf(a2 * sc) | ((unsigned int)f2bf(a3 * sc) << 16);
    o.z = (unsigned int)f2bf(a4 * sc) | ((unsigned int)f2bf(a5 * sc) << 16);
    o.w = (unsigned int)f2bf(a6 * sc) | ((unsigned int)f2bf(a7 * sc) << 16);
    x_out[(size_t)node * 8 + sl] = o;
}

__global__ __launch_bounds__(256, 8) void prop_kernel(
        const uint4* __restrict__ x_in, uint4* __restrict__ x_out,
        const int* __restrict__ ptr, const int* __restrict__ rend,
        const int* __restrict__ src,
        const float* __restrict__ scale) {
    int gid  = blockIdx.x * blockDim.x + threadIdx.x;
    int node = gid >> 3;       // 8 lanes per node
    int sl   = gid & 7;        // lane's 8-dim slot within the row
    if (node > NNODES) return;
    if (node == NNODES) {      // keep sentinel row zero for next layer
        x_out[(size_t)node * 8 + sl] = make_uint4(0u, 0u, 0u, 0u);
        return;
    }
    prop_node(x_in, x_out, ptr, rend, src, scale, node, sl);
}

// layer 3: only nodes consumed downstream — users, items+NUM_USERS, sel_col.
__global__ __launch_bounds__(256, 8) void prop_list_kernel(
        const uint4* __restrict__ x_in, uint4* __restrict__ x_out,
        const int* __restrict__ ptr, const int* __restrict__ rend,
        const int* __restrict__ src,
        const float* __restrict__ scale,
        const int* __restrict__ users, const int* __restrict__ items,
        const int* __restrict__ sel_col, const int* __restrict__ n_sel_p) {
    int n = *n_sel_p; if (n > SEL_CAP) n = SEL_CAP;
    int total = (2 * BATCH + n) * 8;
    int nth = gridDim.x * blockDim.x;
    for (int gid = blockIdx.x * blockDim.x + threadIdx.x; gid < total; gid += nth) {
        int li = gid >> 3;
        int sl = gid & 7;
        int node;
        if (li < BATCH) {
            node = users[li];
        } else if (li < 2 * BATCH) {
            node = items[li - BATCH] + NUM_USERS;
        } else {
            node = sel_col[li - 2 * BATCH];
        }
        prop_node(x_in, x_out, ptr, rend, src, scale, node, sl);
    }
}

// ---- batch part ----------------------------------------------------------

__global__ void ucnt_kernel(const int* __restrict__ users, int* __restrict__ ucnt) {
    int b = blockIdx.x * blockDim.x + threadIdx.x;
    if (b < BATCH) atomicAdd(&ucnt[users[b]], 1);
}

// fused tail (cooperative, 512 blocks x 256): ctx -> softmax -> score
__global__ __launch_bounds__(256) void tail_kernel(
        const unsigned short* __restrict__ x,
        const int* __restrict__ users, const int* __restrict__ items,
        const int* __restrict__ sel_col, const float* __restrict__ sel_w,
        const int* __restrict__ n_sel_p,
        float* __restrict__ ctx, float* __restrict__ S, float* __restrict__ zp,
        float* __restrict__ out) {
    cg::grid_group grid = cg::this_grid();
    __shared__ float sm[256];
    __shared__ float smZ[4];
    int t = threadIdx.x, blk = blockIdx.x;
    int lane = t & 63, wl = t >> 6;
    // phase 1: ctx partial sums (blocks 0..63, 16 users each)
    if (blk < 64) {
        int b0 = blk * 16 + wl * 4;
        float acc = 0.0f;
        #pragma unroll
        for (int k = 0; k < 4; ++k)
            acc += bf2f(x[users[b0 + k] * DIM + lane]);
        sm[t] = acc;
        __syncthreads();
        if (wl == 0)
            atomicAdd(&ctx[lane], sm[lane] + sm[64 + lane] + sm[128 + lane] + sm[192 + lane]);
    }
    grid.sync();
    // phase 2: softmax accumulation over selected edges
    {
        int n = *n_sel_p; if (n > SEL_CAP) n = SEL_CAP;
        float c = ctx[lane] * (1.0f / BATCH);
        float accS = 0.0f, accZ = 0.0f;
        int stride = gridDim.x * 4;
        for (int idx = blk * 4 + wl; idx < n; idx += stride) {
            int node = sel_col[idx];
            float xv = bf2f(x[node * DIM + lane]);
            float v = wave_sum64(xv * c);
            float w = sel_w[idx] * __expf(v);
            accS = fmaf(w, xv, accS);
            accZ += w;
        }
        __syncthreads();   // sm reuse
        sm[wl * 64 + lane] = accS;
        if (lane == 0) smZ[wl] = accZ;
        __syncthreads();
        if (wl == 0) {
            float s = sm[lane] + sm[64 + lane] + sm[128 + lane] + sm[192 + lane];
            atomicAdd(&S[lane], s);
        }
        if (t == 0) atomicAdd(zp, smZ[0] + smZ[1] + smZ[2] + smZ[3]);
    }
    grid.sync();
    // phase 3: scores (first 256 blocks cover 1024 rows x 64 lanes)
    {
        int gid = blk * 256 + t;
        int b = gid >> 6, ln = gid & 63;
        if (b < BATCH) {
            float z = fmaxf(*zp, 1e-12f);
            float na = S[ln] / z;
            int u = users[b], it = items[b] + NUM_USERS;
            float v = bf2f(x[u * DIM + ln]) * (bf2f(x[it * DIM + ln]) + na);
            v = wave_sum64(v);
            if (ln == 0) out[b] = 1.0f / (1.0f + __expf(-v));
        }
    }
}

// ---- launch -------------------------------------------------------------

extern "C" void kernel_launch(void* const* d_in, const int* in_sizes, int n_in,
                              void* d_out, int out_size, void* d_ws, size_t ws_size,
                              hipStream_t stream) {
    const float* embed = (const float*)d_in[0];
    const int*   edge  = (const int*)d_in[1];
    const int*   row   = edge;
    const int*   col   = edge + NEDGE;
    const int*   users = (const int*)d_in[2];
    const int*   items = (const int*)d_in[3];
    float*       out   = (float*)d_out;
    char*        ws    = (char*)d_ws;

    size_t off = 0;
    auto A = [&](size_t bytes) { size_t o = off; off += (bytes + 255) & ~(size_t)255; return o; };
    size_t o_midC2 = A((size_t)NBUK * SLICES * SCAP * 4);   // 19.2 MB
    size_t o_midR2 = A((size_t)NBUK * SLICES * SCAP * 2);   // 9.6 MB
    size_t o_xa    = A((size_t)(NNODES + 1) * DIM * 2);     // +1: sentinel zero row
    size_t o_xb    = A((size_t)(NNODES + 1) * DIM * 2);
    size_t o_src   = A((size_t)NBUK * BCAP * 4);            // 9.6 MB, alive thru prop
    size_t o_cntC8 = A((size_t)SLICES * NBUK);              // 300 KB
    size_t o_cntR8 = A((size_t)SLICES * NBUK);
    size_t o_ovfC  = A((size_t)OVF_CAP * 8);
    size_t o_ovfR  = A((size_t)OVF_CAP * 4);
    size_t o_selc  = A((size_t)SEL_CAP * 4);
    size_t o_selw  = A((size_t)SEL_CAP * 4);
    size_t o_zero  = off;                                   // ---- zeroed block ----
    size_t o_ucnt  = A((size_t)NNODES * 4);
    size_t o_misc  = A(1024);     // n_sel@0, z@8, S@256, ctx@512, novfC@768, novfR@772
    size_t zero_bytes = off - o_zero;                       // ---- end zero -------
    size_t o_dinv  = A((size_t)NNODES * 4);
    size_t o_dinv2 = A((size_t)NNODES * 4);
    size_t o_rptr  = A((size_t)NNODES * 4);
    size_t o_rend  = A((size_t)NNODES * 4);

    unsigned int*   midC2 = (unsigned int*)(ws + o_midC2);
    unsigned short* midR2 = (unsigned short*)(ws + o_midR2);
    unsigned short* xa   = (unsigned short*)(ws + o_xa);
    unsigned short* xb   = (unsigned short*)(ws + o_xb);
    int*   srcS  = (int*)(ws + o_src);
    unsigned char* cntC8 = (unsigned char*)(ws + o_cntC8);
    unsigned char* cntR8 = (unsigned char*)(ws + o_cntR8);
    uint2* ovfC  = (uint2*)(ws + o_ovfC);
    unsigned int* ovfR = (unsigned int*)(ws + o_ovfR);
    int*   selc  = (int*)(ws + o_selc);
    float* selw  = (float*)(ws + o_selw);
    int*   ucnt  = (int*)(ws + o_ucnt);
    int*   nsel  = (int*)(ws + o_misc);
    float* zp    = (float*)(ws + o_misc + 8);
    float* S     = (float*)(ws + o_misc + 256);
    float* ctx   = (float*)(ws + o_misc + 512);
    int*   novfC = (int*)(ws + o_misc + 768);
    int*   novfR = (int*)(ws + o_misc + 772);
    float* dinv  = (float*)(ws + o_dinv);
    float* dinv2 = (float*)(ws + o_dinv2);
    int*   rptr  = (int*)(ws + o_rptr);
    int*   rend  = (int*)(ws + o_rend);

    hipMemsetAsync(ws + o_zero, 0, zero_bytes, stream);

    ucnt_kernel<<<(BATCH + 255) / 256, 256, 0, stream>>>(users, ucnt);

    // single-pass bucket sort, deterministic slotting (no reservation atomics)
    sort_kernel<<<SLICES, 512, 0, stream>>>(row, col, ucnt, cntC8, cntR8,
                                            midC2, midR2, ovfC, ovfR, novfC, novfR,
                                            nsel, selc, selw);
    // split grid: col CSR (NBUK blocks) + row deg/dinv/cvt (NBUK blocks)
    bfinal_kernel<<<2 * NBUK, 1024, 0, stream>>>(midC2, cntC8, midR2, cntR8,
                                                 ovfC, ovfR, novfC, novfR,
                                                 (const float4*)embed, rptr, rend, srcS,
                                                 dinv, dinv2, (uint2*)xa);

    // layers 1,2 full: y->y (dinv2), y->y (dinv2); layer 3 selective: y->x (dinv)
    int prop_blocks = ((NNODES + 1) * 8 + 255) / 256;
    prop_kernel<<<prop_blocks, 256, 0, stream>>>((const uint4*)xa, (uint4*)xb, rptr, rend, srcS, dinv2);
    prop_kernel<<<prop_blocks, 256, 0, stream>>>((const uint4*)xb, (uint4*)xa, rptr, rend, srcS, dinv2);
    prop_list_kernel<<<1024, 256, 0, stream>>>((const uint4*)xa, (uint4*)xb,
                                               rptr, rend, srcS, dinv,
                                               users, items, selc, nsel);
    // final x rows (users/items/sel) live in xb

    // fused tail: ctx -> softmax -> score (one cooperative launch)
    {
        const unsigned short* xb_c = xb;
        void* args[] = { (void*)&xb_c, (void*)&users, (void*)&items,
                         (void*)&selc, (void*)&selw, (void*)&nsel,
                         (void*)&ctx, (void*)&S, (void*)&zp, (void*)&out };
        hipLaunchCooperativeKernel((void*)tail_kernel, dim3(512), dim3(256),
                                   args, 0, stream);
    }
}

// Round 15
// 244.498 us; speedup vs baseline: 1.3992x; 1.3992x over previous
//
#include <hip/hip_runtime.h>
#include <float.h>
#include <math.h>

#define NUM_USERS 100000
#define NUM_ITEMS 50000
#define NNODES    150000
#define DIM       64
#define NEDGE     2000000
#define BATCH     1024
#define SEL_CAP   (1 << 18)
#define LOGIT_BLOCKS 512

#define SLICES   1024                   // edge slices (all blocks resident: 4/CU)
#define EPS      1956                   // ceil(NEDGE/SLICES) rounded to x4
#define NBUK     293                    // buckets of 512 nodes (293*512=150016)
#define BCAP     8192                   // per-bucket CSR arena (exp 6826, +16 sigma)
#define SCAP     16                     // fixed slots per (bucket, slice); exp 6.7
#define OVF_CAP  4096                   // global overflow list (exp ~200 edges/run)
#define MASKW    ((NNODES + 31) / 32)   // user bitmask words

__device__ __forceinline__ float wave_sum64(float v) {
    #pragma unroll
    for (int off = 32; off > 0; off >>= 1) v += __shfl_xor(v, off, 64);
    return v;
}

__device__ __forceinline__ float bf2f(unsigned short s) {
    return __uint_as_float(((unsigned int)s) << 16);
}
__device__ __forceinline__ unsigned short f2bf(float f) {   // RNE
    unsigned int u = __float_as_uint(f);
    return (unsigned short)((u + 0x7fffu + ((u >> 16) & 1u)) >> 16);
}

// ---- bucket sort, single pass, deterministic (bucket,slice) slotting -----
// Selection pre-filtered by an 18.75 KB user bitmask (L1-resident): only
// ~13.6K of 2M edges touch the 600 KB ucnt array.

__global__ __launch_bounds__(512) void sort_kernel(
        const int* __restrict__ row, const int* __restrict__ col,
        const int* __restrict__ ucnt, const unsigned int* __restrict__ umask,
        unsigned char* __restrict__ cntC8, unsigned char* __restrict__ cntR8,
        unsigned int* __restrict__ midC2, unsigned short* __restrict__ midR2,
        uint2* __restrict__ ovfC, unsigned int* __restrict__ ovfR,
        int* __restrict__ novfC_g, int* __restrict__ novfR_g,
        int* __restrict__ n_sel, int* __restrict__ sel_col, float* __restrict__ sel_w) {
    __shared__ unsigned int hc[NBUK], hr[NBUK];
    __shared__ unsigned int   stC[NBUK * SCAP];
    __shared__ unsigned short stR[NBUK * SCAP];
    __shared__ int lcnt, lbase;
    __shared__ int2 buf[256];
    int blk = blockIdx.x, t = threadIdx.x;
    for (int i = t; i < NBUK; i += 512) { hc[i] = 0; hr[i] = 0; }
    if (t == 0) lcnt = 0;
    __syncthreads();
    int e0 = blk * EPS;
    int e1 = e0 + EPS; if (e1 > NEDGE) e1 = NEDGE;
    for (int base = e0 + t * 4; base < e1; base += 2048) {
        if (base + 4 <= e1) {
            int4 r4 = *(const int4*)(row + base);
            int4 c4 = *(const int4*)(col + base);
            #pragma unroll
            for (int q = 0; q < 4; ++q) {
                int c = (q == 0) ? c4.x : (q == 1) ? c4.y : (q == 2) ? c4.z : c4.w;
                int r = (q == 0) ? r4.x : (q == 1) ? r4.y : (q == 2) ? r4.z : r4.w;
                int bc = c >> 9;
                unsigned int kc = atomicAdd(&hc[bc], 1u);
                unsigned int v = ((unsigned int)(c & 511) << 18) | (unsigned int)r;
                if (kc < SCAP) stC[bc * SCAP + kc] = v;
                else { int i = atomicAdd(novfC_g, 1); if (i < OVF_CAP) ovfC[i] = make_uint2((unsigned int)bc, v); }
                int br = r >> 9;
                unsigned int kr = atomicAdd(&hr[br], 1u);
                if (kr < SCAP) stR[br * SCAP + kr] = (unsigned short)(r & 511);
                else { int i = atomicAdd(novfR_g, 1); if (i < OVF_CAP) ovfR[i] = ((unsigned int)br << 9) | (unsigned int)(r & 511); }
                if (umask[r >> 5] & (1u << (r & 31))) {
                    int u = ucnt[r];
                    int i = atomicAdd(&lcnt, 1);
                    if (i < 256) buf[i] = make_int2(c, u);
                }
            }
        } else {
            for (int e = base; e < e1; ++e) {
                int r = row[e], c = col[e];
                int bc = c >> 9;
                unsigned int kc = atomicAdd(&hc[bc], 1u);
                unsigned int v = ((unsigned int)(c & 511) << 18) | (unsigned int)r;
                if (kc < SCAP) stC[bc * SCAP + kc] = v;
                else { int i = atomicAdd(novfC_g, 1); if (i < OVF_CAP) ovfC[i] = make_uint2((unsigned int)bc, v); }
                int br = r >> 9;
                unsigned int kr = atomicAdd(&hr[br], 1u);
                if (kr < SCAP) stR[br * SCAP + kr] = (unsigned short)(r & 511);
                else { int i = atomicAdd(novfR_g, 1); if (i < OVF_CAP) ovfR[i] = ((unsigned int)br << 9) | (unsigned int)(r & 511); }
                if (umask[r >> 5] & (1u << (r & 31))) {
                    int u = ucnt[r];
                    int i = atomicAdd(&lcnt, 1);
                    if (i < 256) buf[i] = make_int2(c, u);
                }
            }
        }
    }
    __syncthreads();
    for (int j = t; j < NBUK * SCAP; j += 512) {
        int b = j >> 4, k = j & (SCAP - 1);
        unsigned int cc = hc[b]; if (cc > SCAP) cc = SCAP;
        if ((unsigned int)k < cc)
            midC2[(size_t)b * (SLICES * SCAP) + blk * SCAP + k] = stC[j];
        unsigned int cr = hr[b]; if (cr > SCAP) cr = SCAP;
        if ((unsigned int)k < cr)
            midR2[(size_t)b * (SLICES * SCAP) + blk * SCAP + k] = stR[j];
    }
    if (t < NBUK) {
        unsigned int cc = hc[t]; if (cc > SCAP) cc = SCAP;
        unsigned int cr = hr[t]; if (cr > SCAP) cr = SCAP;
        cntC8[(size_t)blk * NBUK + t] = (unsigned char)cc;
        cntR8[(size_t)blk * NBUK + t] = (unsigned char)cr;
    }
    if (t == 0) {
        int c = lcnt; c = c < 256 ? c : 256;
        lbase = atomicAdd(n_sel, c);
    }
    __syncthreads();
    int c = lcnt; c = c < 256 ? c : 256;
    int b = lbase;
    for (int i = t; i < c; i += 512) {
        int o = b + i;
        if (o < SEL_CAP) { sel_col[o] = buf[i].x; sel_w[o] = (float)buf[i].y; }
    }
}

// ---- stage 2, split grid: blocks [0,NBUK) col CSR; [NBUK,2*NBUK) row+cvt --
// Col: the count-pass atomic returns each entry's RANK; entries+ranks are
// held in registers (statically indexed), so after the scan the scatter is
// a direct register write — no stage buffer, no second atomic pass.

__global__ __launch_bounds__(1024) void bfinal_kernel(
        const unsigned int* __restrict__ midC2, const unsigned char* __restrict__ cntC8,
        const unsigned short* __restrict__ midR2, const unsigned char* __restrict__ cntR8,
        const uint2* __restrict__ ovfC, const unsigned int* __restrict__ ovfR,
        const int* __restrict__ novfC_g, const int* __restrict__ novfR_g,
        const float4* __restrict__ embed,
        int* __restrict__ rptr, int* __restrict__ rend, int* __restrict__ src_sorted,
        float* __restrict__ dinv, float* __restrict__ dinv2,
        uint2* __restrict__ y0) {
    __shared__ int cnt[512], sm[512];
    __shared__ unsigned char lc[SLICES];
    __shared__ float dinvL[512];
    __shared__ int ovN;
    __shared__ uint2 ovL[64];        // (value, rank) of overflow entries here
    int bb = blockIdx.x, t = threadIdx.x;
    if (bb < NBUK) {
        // ---------------- col CSR for bucket b ----------------
        int b = bb;
        if (t < SLICES) lc[t] = cntC8[(size_t)t * NBUK + b];
        if (t < 512) cnt[t] = 0;
        if (t == 0) ovN = 0;
        __syncthreads();
        size_t cbase = (size_t)b * (SLICES * SCAP);
        unsigned int vbuf[16];
        int kbuf[16];
        #pragma unroll
        for (int it = 0; it < 16; ++it) {
            int j = t + it * 1024;
            unsigned int v = 0xFFFFFFFFu;
            int k = 0;
            if ((unsigned int)(j & (SCAP - 1)) < (unsigned int)lc[j >> 4]) {
                v = midC2[cbase + j];
                k = atomicAdd(&cnt[v >> 18], 1);
            }
            vbuf[it] = v; kbuf[it] = k;
        }
        int noC = *novfC_g; if (noC > OVF_CAP) noC = OVF_CAP;
        for (int i = t; i < noC; i += 1024) {
            if ((int)ovfC[i].x == b) {
                unsigned int v = ovfC[i].y;
                int k = atomicAdd(&cnt[v >> 18], 1);
                int id = atomicAdd(&ovN, 1);
                if (id < 64) ovL[id] = make_uint2(v, (unsigned int)k);
            }
        }
        __syncthreads();
        if (t < 512) sm[t] = cnt[t];
        __syncthreads();
        for (int off = 1; off < 512; off <<= 1) {
            int v = 0;
            if (t < 512 && t >= off) v = sm[t - off];
            __syncthreads();
            if (t < 512) sm[t] += v;
            __syncthreads();
        }
        int s0 = b * BCAP;
        if (t < 512) {
            int excl = s0 + sm[t] - cnt[t];
            int n = b * 512 + t;
            if (n < NNODES) { rptr[n] = excl; rend[n] = s0 + sm[t]; }
        }
        __syncthreads();
        // direct scatter from registers: dst = excl[node] + rank
        #pragma unroll
        for (int it = 0; it < 16; ++it) {
            unsigned int v = vbuf[it];
            if (v != 0xFFFFFFFFu) {
                int node = (int)(v >> 18);
                int dst = s0 + sm[node] - cnt[node] + kbuf[it];
                src_sorted[dst] = (int)(v & 0x3FFFFu);
            }
        }
        int on = ovN; on = on < 64 ? on : 64;
        for (int i = t; i < on; i += 1024) {
            unsigned int v = ovL[i].x;
            int node = (int)(v >> 18);
            int dst = s0 + sm[node] - cnt[node] + (int)ovL[i].y;
            src_sorted[dst] = (int)(v & 0x3FFFFu);
        }
    } else {
        // ---------------- row deg + dinv + cvt for bucket b ----------------
        int b = bb - NBUK;
        if (t < SLICES) lc[t] = cntR8[(size_t)t * NBUK + b];
        if (t < 512) cnt[t] = 0;
        __syncthreads();
        size_t cbase = (size_t)b * (SLICES * SCAP);
        for (int j = t; j < SLICES * SCAP; j += 1024) {
            if ((unsigned int)(j & (SCAP - 1)) < (unsigned int)lc[j >> 4])
                atomicAdd(&cnt[midR2[cbase + j]], 1);
        }
        int noR = *novfR_g; if (noR > OVF_CAP) noR = OVF_CAP;
        for (int i = t; i < noR; i += 1024) {
            unsigned int pv = ovfR[i];
            if ((int)(pv >> 9) == b) atomicAdd(&cnt[pv & 511u], 1);
        }
        if (b == 0 && t < 16) y0[(size_t)NNODES * 16 + t] = make_uint2(0u, 0u); // sentinel
        __syncthreads();
        if (t < 512) {
            int n = b * 512 + t;
            if (n < NNODES) {
                float d = fmaxf((float)cnt[t], 1.0f);
                float di = rsqrtf(d);
                dinv[n] = di; dinv2[n] = 1.0f / d;
                dinvL[t] = di;
            }
        }
        __syncthreads();
        int nbase = b * 512;
        int nmax = NNODES - nbase; if (nmax > 512) nmax = 512;
        if (nmax < 0) nmax = 0;
        for (int i = t; i < nmax * 16; i += 1024) {
            int ln = i >> 4, slot = i & 15;
            float d = dinvL[ln];
            float4 v = embed[(size_t)(nbase + ln) * 16 + slot];
            unsigned int w0 = (unsigned int)f2bf(v.x * d) | ((unsigned int)f2bf(v.y * d) << 16);
            unsigned int w1 = (unsigned int)f2bf(v.z * d) | ((unsigned int)f2bf(v.w * d) << 16);
            y0[(size_t)(nbase + ln) * 16 + slot] = make_uint2(w0, w1);
        }
    }
}

// ---- propagation: 8 lanes/node, uint4 (8 bf16)/lane; src-prefetch pipeline,
//      parallel sentinel tail (node NNODES is an always-zero row) -----------

#define ACC8(V) do { \
    a0 += __uint_as_float((V).x << 16); a1 += __uint_as_float((V).x & 0xffff0000u); \
    a2 += __uint_as_float((V).y << 16); a3 += __uint_as_float((V).y & 0xffff0000u); \
    a4 += __uint_as_float((V).z << 16); a5 += __uint_as_float((V).z & 0xffff0000u); \
    a6 += __uint_as_float((V).w << 16); a7 += __uint_as_float((V).w & 0xffff0000u); \
} while (0)

__device__ __forceinline__ void prop_node(
        const uint4* __restrict__ x_in, uint4* __restrict__ x_out,
        const int* __restrict__ ptr, const int* __restrict__ rend,
        const int* __restrict__ src,
        const float* __restrict__ scale, int node, int sl) {
    int i = ptr[node], e = rend[node];
    float sc = scale[node];
    float a0 = 0.f, a1 = 0.f, a2 = 0.f, a3 = 0.f;
    float a4 = 0.f, a5 = 0.f, a6 = 0.f, a7 = 0.f;
    int p0, p1, p2, p3;
    if (i + 4 <= e) { p0 = src[i]; p1 = src[i + 1]; p2 = src[i + 2]; p3 = src[i + 3]; }
    while (i + 8 <= e) {
        uint4 w0 = x_in[p0 * 8 + sl];
        uint4 w1 = x_in[p1 * 8 + sl];
        uint4 w2 = x_in[p2 * 8 + sl];
        uint4 w3 = x_in[p3 * 8 + sl];
        p0 = src[i + 4]; p1 = src[i + 5]; p2 = src[i + 6]; p3 = src[i + 7];
        i += 4;
        ACC8(w0); ACC8(w1); ACC8(w2); ACC8(w3);
    }
    if (i + 4 <= e) {
        uint4 w0 = x_in[p0 * 8 + sl];
        uint4 w1 = x_in[p1 * 8 + sl];
        uint4 w2 = x_in[p2 * 8 + sl];
        uint4 w3 = x_in[p3 * 8 + sl];
        i += 4;
        ACC8(w0); ACC8(w1); ACC8(w2); ACC8(w3);
    }
    if (i < e) {               // tail 1..3: clamp to sentinel zero row
        int q0 = src[i];
        int q1 = (i + 1 < e) ? src[i + 1] : NNODES;
        int q2 = (i + 2 < e) ? src[i + 2] : NNODES;
        uint4 w0 = x_in[q0 * 8 + sl];
        uint4 w1 = x_in[q1 * 8 + sl];
        uint4 w2 = x_in[q2 * 8 + sl];
        ACC8(w0); ACC8(w1); ACC8(w2);
    }
    uint4 o;
    o.x = (unsigned int)f2bf(a0 * sc) | ((unsigned int)f2bf(a1 * sc) << 16);
    o.y = (unsigned int)f2bf(a2 * sc) | ((unsigned int)f2bf(a3 * sc) << 16);
    o.z = (unsigned int)f2bf(a4 * sc) | ((unsigned int)f2bf(a5 * sc) << 16);
    o.w = (unsigned int)f2bf(a6 * sc) | ((unsigned int)f2bf(a7 * sc) << 16);
    x_out[(size_t)node * 8 + sl] = o;
}

__global__ __launch_bounds__(256, 8) void prop_kernel(
        const uint4* __restrict__ x_in, uint4* __restrict__ x_out,
        const int* __restrict__ ptr, const int* __restrict__ rend,
        const int* __restrict__ src,
        const float* __restrict__ scale) {
    int gid  = blockIdx.x * blockDim.x + threadIdx.x;
    int node = gid >> 3;       // 8 lanes per node
    int sl   = gid & 7;        // lane's 8-dim slot within the row
    if (node > NNODES) return;
    if (node == NNODES) {      // keep sentinel row zero for next layer
        x_out[(size_t)node * 8 + sl] = make_uint4(0u, 0u, 0u, 0u);
        return;
    }
    prop_node(x_in, x_out, ptr, rend, src, scale, node, sl);
}

// layer 3: only nodes consumed downstream — users, items+NUM_USERS, sel_col.
__global__ __launch_bounds__(256, 8) void prop_list_kernel(
        const uint4* __restrict__ x_in, uint4* __restrict__ x_out,
        const int* __restrict__ ptr, const int* __restrict__ rend,
        const int* __restrict__ src,
        const float* __restrict__ scale,
        const int* __restrict__ users, const int* __restrict__ items,
        const int* __restrict__ sel_col, const int* __restrict__ n_sel_p) {
    int n = *n_sel_p; if (n > SEL_CAP) n = SEL_CAP;
    int total = (2 * BATCH + n) * 8;
    int nth = gridDim.x * blockDim.x;
    for (int gid = blockIdx.x * blockDim.x + threadIdx.x; gid < total; gid += nth) {
        int li = gid >> 3;
        int sl = gid & 7;
        int node;
        if (li < BATCH) {
            node = users[li];
        } else if (li < 2 * BATCH) {
            node = items[li - BATCH] + NUM_USERS;
        } else {
            node = sel_col[li - 2 * BATCH];
        }
        prop_node(x_in, x_out, ptr, rend, src, scale, node, sl);
    }
}

// ---- batch / softmax part (x is bf16) -----------------------------------

__global__ void ucnt_kernel(const int* __restrict__ users, int* __restrict__ ucnt,
                            unsigned int* __restrict__ umask) {
    int b = blockIdx.x * blockDim.x + threadIdx.x;
    if (b < BATCH) {
        int u = users[b];
        atomicAdd(&ucnt[u], 1);
        atomicOr(&umask[u >> 5], 1u << (u & 31));
    }
}

// 64 blocks x 16 users; one atomicAdd per lane into zeroed ctx (raw sum).
__global__ __launch_bounds__(256) void ctx_part_kernel(
        const unsigned short* __restrict__ x, const int* __restrict__ users,
        float* __restrict__ ctx) {
    __shared__ float sm[256];
    int lane = threadIdx.x & 63, wl = threadIdx.x >> 6;
    int b0 = blockIdx.x * 16 + wl * 4;
    float acc = 0.0f;
    #pragma unroll
    for (int k = 0; k < 4; ++k)
        acc += bf2f(x[users[b0 + k] * DIM + lane]);
    sm[threadIdx.x] = acc;
    __syncthreads();
    if (wl == 0)
        atomicAdd(&ctx[lane], sm[lane] + sm[64 + lane] + sm[128 + lane] + sm[192 + lane]);
}

__global__ void softmax_kernel(const unsigned short* __restrict__ x,
                               const float* __restrict__ ctx,
                               const int* __restrict__ sel_col,
                               const float* __restrict__ sel_w,
                               const int* __restrict__ n_sel_p,
                               float* __restrict__ S, float* __restrict__ zp) {
    __shared__ float smS[4 * 64];
    __shared__ float smZ[4];
    int lane = threadIdx.x & 63, wl = threadIdx.x >> 6;
    int n = *n_sel_p; if (n > SEL_CAP) n = SEL_CAP;
    float c = ctx[lane] * (1.0f / BATCH);   // ctx holds raw sum over users
    float accS = 0.0f, accZ = 0.0f;
    int stride = gridDim.x * 4;
    for (int idx = blockIdx.x * 4 + wl; idx < n; idx += stride) {
        int node = sel_col[idx];
        float xv = bf2f(x[node * DIM + lane]);
        float v = wave_sum64(xv * c);
        float w = sel_w[idx] * __expf(v);
        accS = fmaf(w, xv, accS);
        accZ += w;
    }
    smS[wl * 64 + lane] = accS;
    if (lane == 0) smZ[wl] = accZ;
    __syncthreads();
    if (wl == 0) {
        float s = smS[lane] + smS[64 + lane] + smS[128 + lane] + smS[192 + lane];
        atomicAdd(&S[lane], s);
    }
    if (threadIdx.x == 0) atomicAdd(zp, smZ[0] + smZ[1] + smZ[2] + smZ[3]);
}

__global__ void score_kernel(const unsigned short* __restrict__ x, const int* __restrict__ users,
                             const int* __restrict__ items, const float* __restrict__ S,
                             const float* __restrict__ zp, float* __restrict__ out) {
    int gid = blockIdx.x * blockDim.x + threadIdx.x;
    int b = gid >> 6, lane = gid & 63;
    if (b >= BATCH) return;
    float z = fmaxf(*zp, 1e-12f);
    float na = S[lane] / z;
    int u = users[b], it = items[b] + NUM_USERS;
    float v = bf2f(x[u * DIM + lane]) * (bf2f(x[it * DIM + lane]) + na);
    v = wave_sum64(v);
    if (lane == 0) out[b] = 1.0f / (1.0f + __expf(-v));
}

// ---- launch -------------------------------------------------------------

extern "C" void kernel_launch(void* const* d_in, const int* in_sizes, int n_in,
                              void* d_out, int out_size, void* d_ws, size_t ws_size,
                              hipStream_t stream) {
    const float* embed = (const float*)d_in[0];
    const int*   edge  = (const int*)d_in[1];
    const int*   row   = edge;
    const int*   col   = edge + NEDGE;
    const int*   users = (const int*)d_in[2];
    const int*   items = (const int*)d_in[3];
    float*       out   = (float*)d_out;
    char*        ws    = (char*)d_ws;

    size_t off = 0;
    auto A = [&](size_t bytes) { size_t o = off; off += (bytes + 255) & ~(size_t)255; return o; };
    size_t o_midC2 = A((size_t)NBUK * SLICES * SCAP * 4);   // 19.2 MB
    size_t o_midR2 = A((size_t)NBUK * SLICES * SCAP * 2);   // 9.6 MB
    size_t o_xa    = A((size_t)(NNODES + 1) * DIM * 2);     // +1: sentinel zero row
    size_t o_xb    = A((size_t)(NNODES + 1) * DIM * 2);
    size_t o_src   = A((size_t)NBUK * BCAP * 4);            // 9.6 MB, alive thru prop
    size_t o_cntC8 = A((size_t)SLICES * NBUK);              // 300 KB
    size_t o_cntR8 = A((size_t)SLICES * NBUK);
    size_t o_ovfC  = A((size_t)OVF_CAP * 8);
    size_t o_ovfR  = A((size_t)OVF_CAP * 4);
    size_t o_selc  = A((size_t)SEL_CAP * 4);
    size_t o_selw  = A((size_t)SEL_CAP * 4);
    size_t o_zero  = off;                                   // ---- zeroed block ----
    size_t o_ucnt  = A((size_t)NNODES * 4);
    size_t o_umask = A((size_t)MASKW * 4);                  // 18.75 KB user bitmask
    size_t o_misc  = A(1024);     // n_sel@0, z@8, S@256, ctx@512, novfC@768, novfR@772
    size_t zero_bytes = off - o_zero;                       // ---- end zero -------
    size_t o_dinv  = A((size_t)NNODES * 4);
    size_t o_dinv2 = A((size_t)NNODES * 4);
    size_t o_rptr  = A((size_t)NNODES * 4);
    size_t o_rend  = A((size_t)NNODES * 4);

    unsigned int*   midC2 = (unsigned int*)(ws + o_midC2);
    unsigned short* midR2 = (unsigned short*)(ws + o_midR2);
    unsigned short* xa   = (unsigned short*)(ws + o_xa);
    unsigned short* xb   = (unsigned short*)(ws + o_xb);
    int*   srcS  = (int*)(ws + o_src);
    unsigned char* cntC8 = (unsigned char*)(ws + o_cntC8);
    unsigned char* cntR8 = (unsigned char*)(ws + o_cntR8);
    uint2* ovfC  = (uint2*)(ws + o_ovfC);
    unsigned int* ovfR = (unsigned int*)(ws + o_ovfR);
    int*   selc  = (int*)(ws + o_selc);
    float* selw  = (float*)(ws + o_selw);
    int*   ucnt  = (int*)(ws + o_ucnt);
    unsigned int* umask = (unsigned int*)(ws + o_umask);
    int*   nsel  = (int*)(ws + o_misc);
    float* zp    = (float*)(ws + o_misc + 8);
    float* S     = (float*)(ws + o_misc + 256);
    float* ctx   = (float*)(ws + o_misc + 512);
    int*   novfC = (int*)(ws + o_misc + 768);
    int*   novfR = (int*)(ws + o_misc + 772);
    float* dinv  = (float*)(ws + o_dinv);
    float* dinv2 = (float*)(ws + o_dinv2);
    int*   rptr  = (int*)(ws + o_rptr);
    int*   rend  = (int*)(ws + o_rend);

    hipMemsetAsync(ws + o_zero, 0, zero_bytes, stream);

    ucnt_kernel<<<(BATCH + 255) / 256, 256, 0, stream>>>(users, ucnt, umask);

    // single-pass bucket sort, deterministic slotting (no reservation atomics)
    sort_kernel<<<SLICES, 512, 0, stream>>>(row, col, ucnt, umask, cntC8, cntR8,
                                            midC2, midR2, ovfC, ovfR, novfC, novfR,
                                            nsel, selc, selw);
    // split grid: col CSR (NBUK blocks) + row deg/dinv/cvt (NBUK blocks)
    bfinal_kernel<<<2 * NBUK, 1024, 0, stream>>>(midC2, cntC8, midR2, cntR8,
                                                 ovfC, ovfR, novfC, novfR,
                                                 (const float4*)embed, rptr, rend, srcS,
                                                 dinv, dinv2, (uint2*)xa);

    // layers 1,2 full: y->y (dinv2), y->y (dinv2); layer 3 selective: y->x (dinv)
    int prop_blocks = ((NNODES + 1) * 8 + 255) / 256;
    prop_kernel<<<prop_blocks, 256, 0, stream>>>((const uint4*)xa, (uint4*)xb, rptr, rend, srcS, dinv2);
    prop_kernel<<<prop_blocks, 256, 0, stream>>>((const uint4*)xb, (uint4*)xa, rptr, rend, srcS, dinv2);
    prop_list_kernel<<<1024, 256, 0, stream>>>((const uint4*)xa, (uint4*)xb,
                                               rptr, rend, srcS, dinv,
                                               users, items, selc, nsel);
    // final x rows (users/items/sel) live in xb

    // batch softmax aggregation over selected edges (mx = 0, fused)
    ctx_part_kernel<<<64, 256, 0, stream>>>(xb, users, ctx);
    softmax_kernel<<<LOGIT_BLOCKS, 256, 0, stream>>>(xb, ctx, selc, selw, nsel, S, zp);

    // final scores
    score_kernel<<<(BATCH * 64 + 255) / 256, 256, 0, stream>>>(xb, users, items, S, zp, out);
}